// Round 3
// baseline (590.741 us; speedup 1.0000x reference)
//
#include <hip/hip_runtime.h>
#include <hip/hip_bf16.h>

#define JOINTS   22
#define SEQ      176
#define DIN      128
#define NHEAD    8
#define HD       64
#define DMODEL   512
#define NMT      11

typedef __bf16 bf16x8 __attribute__((ext_vector_type(8)));
typedef float  f32x4  __attribute__((ext_vector_type(4)));
typedef float  f32x16 __attribute__((ext_vector_type(16)));

__device__ __forceinline__ unsigned short f2bf(float f) {
  __hip_bfloat16 h = __float2bfloat16(f);
  return __builtin_bit_cast(unsigned short, h);
}
__device__ __forceinline__ float bf2f(unsigned short u) {
  __hip_bfloat16 h = __builtin_bit_cast(__hip_bfloat16, u);
  return __bfloat162float(h);
}

// ---------------- workspace layout (ushort elements) ----------------
#define WT_E    0u            // [3][512][128] bf16  W^T (Wq pre-scaled 0.125)
#define BIAS_E  196608u       // [3][512] bf16       (bq pre-scaled)
#define Q_E     198144u       // [4096][176][64] bf16
#define PERQKV  46137344u
#define K_E     (Q_E + PERQKV)
#define V_E     (K_E + PERQKV)   // [4096][64][176] bf16 (transposed, ReLU'd)
#define WS_NEED ((size_t)(V_E + PERQKV) * 2)

// ================== kernel 0: W transpose + bias prep ==================
__global__ __launch_bounds__(256) void prep_kernel(
    const float* __restrict__ Wq, const float* __restrict__ bq,
    const float* __restrict__ Wk, const float* __restrict__ bk,
    const float* __restrict__ Wv, const float* __restrict__ bv,
    unsigned short* __restrict__ ws)
{
  int idx = blockIdx.x * 256 + threadIdx.x;        // < 196608
  int which = idx >> 16;                           // 0..2
  int rem = idx & 65535;
  int n = rem >> 7, k = rem & 127;
  const float* W = (which == 0) ? Wq : (which == 1 ? Wk : Wv);
  float scale = (which == 0) ? 0.125f : 1.0f;
  ws[WT_E + idx] = f2bf(W[k * DMODEL + n] * scale);
  if (idx < 1536) {
    int w2 = idx >> 9, n2 = idx & 511;
    const float* bb = (w2 == 0) ? bq : (w2 == 1 ? bk : bv);
    float s2 = (w2 == 0) ? 0.125f : 1.0f;
    ws[BIAS_E + idx] = f2bf(bb[n2] * s2);
  }
}

// ================== kernel A: QKV projection GEMM ==================
// grid (704 m-blocks, 4 n-blocks), 256 threads. Tile 128x128, K=128.
__global__ __launch_bounds__(256) void qkv_gemm_kernel(
    const float* __restrict__ x, unsigned short* __restrict__ ws)
{
  __shared__ unsigned short Xs[128 * 136];
  __shared__ unsigned short Wt[128 * 136];
  const int tid  = threadIdx.x;
  const int lane = tid & 63, wave = tid >> 6;
  const int l15  = lane & 15, quad = lane >> 4;
  const int m0 = blockIdx.x * 128;
  const int nb = blockIdx.y;                        // 0..3
  const int wm = (wave >> 1) * 64, wn = (wave & 1) * 64;

  // stage X tile fp32 -> bf16 (coalesced float4)
  {
    const float4* x4 = reinterpret_cast<const float4*>(x + (size_t)m0 * DIN);
    #pragma unroll
    for (int i = 0; i < 16; ++i) {
      int c = tid + i * 256;                        // < 4096
      int row = c >> 5, col4 = c & 31;
      float4 v = x4[c];
      uint2 pk;
      pk.x = (unsigned)f2bf(v.x) | ((unsigned)f2bf(v.y) << 16);
      pk.y = (unsigned)f2bf(v.z) | ((unsigned)f2bf(v.w) << 16);
      *reinterpret_cast<uint2*>(&Xs[row * 136 + col4 * 4]) = pk;
    }
  }

  for (int which = 0; which < 3; ++which) {
    __syncthreads();     // protect Wt from prior-iter readers (also covers Xs)
    {
      const uint4* wsrc = reinterpret_cast<const uint4*>(
          ws + WT_E + which * 65536 + nb * 128 * 128);
      #pragma unroll
      for (int i = 0; i < 8; ++i) {
        int c = tid + i * 256;                      // < 2048
        int row = c >> 4, col8 = c & 15;
        *reinterpret_cast<uint4*>(&Wt[row * 136 + col8 * 8]) = wsrc[c];
      }
    }
    __syncthreads();

    f32x4 acc[16];
    #pragma unroll
    for (int i = 0; i < 16; ++i) acc[i] = (f32x4){0.f, 0.f, 0.f, 0.f};

    #pragma unroll
    for (int kk = 0; kk < 4; ++kk) {
      bf16x8 a[4], bfr[4];
      #pragma unroll
      for (int mt = 0; mt < 4; ++mt)
        a[mt] = *reinterpret_cast<const bf16x8*>(
            &Xs[(wm + mt * 16 + l15) * 136 + kk * 32 + quad * 8]);
      #pragma unroll
      for (int nt = 0; nt < 4; ++nt)
        bfr[nt] = *reinterpret_cast<const bf16x8*>(
            &Wt[(wn + nt * 16 + l15) * 136 + kk * 32 + quad * 8]);
      if (which != 2) {
        #pragma unroll
        for (int mt = 0; mt < 4; ++mt)
          #pragma unroll
          for (int nt = 0; nt < 4; ++nt)
            acc[mt * 4 + nt] = __builtin_amdgcn_mfma_f32_16x16x32_bf16(
                a[mt], bfr[nt], acc[mt * 4 + nt], 0, 0, 0);
      } else {   // swapped operands -> C[n][m] for transposed V store
        #pragma unroll
        for (int mt = 0; mt < 4; ++mt)
          #pragma unroll
          for (int nt = 0; nt < 4; ++nt)
            acc[mt * 4 + nt] = __builtin_amdgcn_mfma_f32_16x16x32_bf16(
                bfr[nt], a[mt], acc[mt * 4 + nt], 0, 0, 0);
      }
    }

    if (which != 2) {      // Q / K: store [BH][S][64]
      unsigned short* dst = ws + ((which == 0) ? Q_E : K_E);
      #pragma unroll
      for (int nt = 0; nt < 4; ++nt) {
        int c = nb * 128 + wn + nt * 16 + l15;
        float bs = bf2f(ws[BIAS_E + which * 512 + c]);
        int h = c >> 6, d = c & 63;
        #pragma unroll
        for (int mt = 0; mt < 4; ++mt) {
          #pragma unroll
          for (int r = 0; r < 4; ++r) {
            int g = m0 + wm + mt * 16 + quad * 4 + r;
            int b_ = g / 176, s = g - b_ * 176;
            dst[((size_t)(b_ * 8 + h) * 176 + s) * 64 + d] =
                f2bf(acc[mt * 4 + nt][r] + bs);
          }
        }
      }
    } else {               // V: ReLU, store transposed [BH][64][S]
      unsigned short* dst = ws + V_E;
      #pragma unroll
      for (int nt = 0; nt < 4; ++nt) {
        #pragma unroll
        for (int r = 0; r < 4; ++r) {
          int c = nb * 128 + wn + nt * 16 + quad * 4 + r;
          int h = c >> 6, d = c & 63;
          float bs = bf2f(ws[BIAS_E + 1024 + c]);
          #pragma unroll
          for (int mt = 0; mt < 4; ++mt) {
            int g = m0 + wm + mt * 16 + l15;
            int b_ = g / 176, s = g - b_ * 176;
            float val = fmaxf(acc[mt * 4 + nt][r] + bs, 0.f);
            dst[((size_t)(b_ * 8 + h) * 64 + d) * 176 + s] = f2bf(val);
          }
        }
      }
    }
  }
}

// ================== kernel B: attention v4 (32x32x16 MFMA) ==================
// One 384-thread (6-wave) block per (b,h); wave w owns q-tile [32w, 32w+32)
// (tile 5 is half-dummy, stores guarded). Swapped QK^T (mfma(K,Q)) -> lane
// (l31=q, hi) + partner hold the full P row: softmax is lane-local + one
// shfl_xor(32) for max and one for sum. P stays IN REGISTERS for PV: the
// MFMA k-positions are permuted identically on the A side (P regs as-is)
// and the B side (two ds_read_b64 from Vt at the matching permuted offsets),
// so no cross-lane exchange and no P LDS buffer are needed.
// LDS = Ks[192*66] + Vt[64*194] = 49 KB; strides 33/97 dw are conflict-free.
#define KLD32 66
#define VLD32 194

__global__ __launch_bounds__(384, 3) void attn_kernel(
    const unsigned short* __restrict__ ws, float* __restrict__ out)
{
  __shared__ unsigned short Ks[192 * KLD32];    // 25344 B (rows 176..191 = 0)
  __shared__ unsigned short Vt[HD * VLD32];     // 24832 B (cols 176..191 = 0)

  const int tid  = threadIdx.x;
  const int lane = tid & 63, wave = tid >> 6;   // wave = m-tile 0..5
  const int l31  = lane & 31, hi = lane >> 5;
  const int bh = blockIdx.x;
  const int b = bh >> 3, h = bh & 7;

  const unsigned short* qp = ws + Q_E + (size_t)bh * 11264;
  const unsigned short* kp = ws + K_E + (size_t)bh * 11264;
  const unsigned short* vp = ws + V_E + (size_t)bh * 11264;

  // ---- Q prefetch (B-fragment: row q = wave*32 + l31, d = dt*16 + hi*8 + j)
  // q may reach 191 (tile-5 dummy rows): reads land inside ws - safe.
  const int q = wave * 32 + l31;
  bf16x8 aq[4];
  #pragma unroll
  for (int dt = 0; dt < 4; ++dt)
    aq[dt] = *reinterpret_cast<const bf16x8*>(qp + q * 64 + dt * 16 + hi * 8);

  // ---- stage K: 192 rows x 8 uint4 = 1536 chunks (rows >=176 zeroed)
  {
    const uint4* ks4 = reinterpret_cast<const uint4*>(kp);
    const uint4 z = {0u, 0u, 0u, 0u};
    #pragma unroll
    for (int i = 0; i < 4; ++i) {
      int c = tid + i * 384;                    // < 1536
      int row = c >> 3, col = c & 7;
      uint4 v = (c < 1408) ? ks4[c] : z;
      *reinterpret_cast<uint4*>(&Ks[row * KLD32 + col * 8]) = v;
    }
  }
  // ---- stage V^T: 64 rows x 22 uint4 = 1408 + 128 zero chunks (cols 176..191)
  {
    const uint4* vs4 = reinterpret_cast<const uint4*>(vp);
    const uint4 z = {0u, 0u, 0u, 0u};
    #pragma unroll
    for (int i = 0; i < 4; ++i) {
      int c = tid + i * 384;                    // < 1536
      if (c < 1408) {
        int row = c / 22, col = c - row * 22;
        *reinterpret_cast<uint4*>(&Vt[row * VLD32 + col * 8]) = vs4[c];
      } else {
        int c2 = c - 1408;                      // < 128
        int row = c2 >> 1, col = c2 & 1;
        *reinterpret_cast<uint4*>(&Vt[row * VLD32 + 176 + col * 8]) = z;
      }
    }
  }
  __syncthreads();

  // ---- QK^T: sc[nt][reg] = P-score at k = nt*32 + (reg&3) + 8*(reg>>2) + 4*hi
  f32x16 sc[6];
  #pragma unroll
  for (int nt = 0; nt < 6; ++nt) {
    f32x16 acc;
    #pragma unroll
    for (int zz = 0; zz < 16; ++zz) acc[zz] = 0.f;
    #pragma unroll
    for (int dt = 0; dt < 4; ++dt) {
      bf16x8 kf = *reinterpret_cast<const bf16x8*>(
          &Ks[(nt * 32 + l31) * KLD32 + dt * 16 + hi * 8]);
      acc = __builtin_amdgcn_mfma_f32_32x32x16_bf16(kf, aq[dt], acc, 0, 0, 0);
    }
    sc[nt] = acc;
  }

  // ---- mask + softmax (lane owns column q; partner lane^32 has other half)
  const int lo   = (q / JOINTS) * JOINTS;
  const int hifr = lo + JOINTS;
  float mxa0 = -3.0e38f, mxa1 = -3.0e38f, mxa2 = -3.0e38f, mxa3 = -3.0e38f;
  #pragma unroll
  for (int nt = 0; nt < 6; ++nt) {
    #pragma unroll
    for (int reg = 0; reg < 16; ++reg) {
      int k = nt * 32 + (reg & 3) + 8 * (reg >> 2) + 4 * hi;
      bool msk = (k >= SEQ) || ((k >= lo) && (k < hifr) && (k != q));
      float v = msk ? -1.0e30f : sc[nt][reg];
      sc[nt][reg] = v;
      if ((reg & 3) == 0) mxa0 = fmaxf(mxa0, v);
      else if ((reg & 3) == 1) mxa1 = fmaxf(mxa1, v);
      else if ((reg & 3) == 2) mxa2 = fmaxf(mxa2, v);
      else mxa3 = fmaxf(mxa3, v);
    }
  }
  float mx = fmaxf(fmaxf(mxa0, mxa1), fmaxf(mxa2, mxa3));
  mx = fmaxf(mx, __shfl_xor(mx, 32));

  float sa0 = 0.f, sa1 = 0.f, sa2 = 0.f, sa3 = 0.f;
  #pragma unroll
  for (int nt = 0; nt < 6; ++nt) {
    #pragma unroll
    for (int reg = 0; reg < 16; ++reg) {
      float e = __expf(sc[nt][reg] - mx);
      sc[nt][reg] = e;
      if ((reg & 3) == 0) sa0 += e;
      else if ((reg & 3) == 1) sa1 += e;
      else if ((reg & 3) == 2) sa2 += e;
      else sa3 += e;
    }
  }
  float sum = (sa0 + sa1) + (sa2 + sa3);
  sum += __shfl_xor(sum, 32);
  float rinv = 1.0f / sum;

  // ---- normalize + pack: pa[nt][half] = regs [8*half .. 8*half+7] as bf16x8
  uint4 pa[6][2];
  #pragma unroll
  for (int nt = 0; nt < 6; ++nt) {
    #pragma unroll
    for (int hf = 0; hf < 2; ++hf) {
      unsigned w0, w1, w2, w3;
      {
        float a0 = sc[nt][hf * 8 + 0] * rinv, a1 = sc[nt][hf * 8 + 1] * rinv;
        float a2 = sc[nt][hf * 8 + 2] * rinv, a3 = sc[nt][hf * 8 + 3] * rinv;
        float a4 = sc[nt][hf * 8 + 4] * rinv, a5 = sc[nt][hf * 8 + 5] * rinv;
        float a6 = sc[nt][hf * 8 + 6] * rinv, a7 = sc[nt][hf * 8 + 7] * rinv;
        w0 = (unsigned)f2bf(a0) | ((unsigned)f2bf(a1) << 16);
        w1 = (unsigned)f2bf(a2) | ((unsigned)f2bf(a3) << 16);
        w2 = (unsigned)f2bf(a4) | ((unsigned)f2bf(a5) << 16);
        w3 = (unsigned)f2bf(a6) | ((unsigned)f2bf(a7) << 16);
      }
      pa[nt][hf].x = w0; pa[nt][hf].y = w1; pa[nt][hf].z = w2; pa[nt][hf].w = w3;
    }
  }

  // ---- PV: A = P regs (k-order: tile (nt,hf), elem j -> k = nt*32 + 16*hf +
  // 4*hi + (j&3) + 8*(j>>2)); B read from Vt with the SAME permuted order:
  // two b64 at [base] and [base+8]. k in [176,192) has P=0 and Vt=0.
  f32x16 ov[2];
  #pragma unroll
  for (int dt = 0; dt < 2; ++dt) {
    #pragma unroll
    for (int zz = 0; zz < 16; ++zz) ov[dt][zz] = 0.f;
  }
  #pragma unroll
  for (int nt = 0; nt < 6; ++nt) {
    #pragma unroll
    for (int hf = 0; hf < 2; ++hf) {
      bf16x8 af = __builtin_bit_cast(bf16x8, pa[nt][hf]);
      const int base = nt * 32 + 16 * hf + 4 * hi;
      #pragma unroll
      for (int dt = 0; dt < 2; ++dt) {
        const unsigned short* vrow = &Vt[(dt * 32 + l31) * VLD32];
        uint2 blo = *reinterpret_cast<const uint2*>(vrow + base);
        uint2 bhi = *reinterpret_cast<const uint2*>(vrow + base + 8);
        uint4 bb4; bb4.x = blo.x; bb4.y = blo.y; bb4.z = bhi.x; bb4.w = bhi.y;
        bf16x8 bf = __builtin_bit_cast(bf16x8, bb4);
        ov[dt] = __builtin_amdgcn_mfma_f32_32x32x16_bf16(af, bf, ov[dt], 0, 0, 0);
      }
    }
  }

  // ---- store: C[row = q-local][col = d-local]; rows q >= 176 guarded
  #pragma unroll
  for (int dt = 0; dt < 2; ++dt) {
    int d = dt * 32 + l31;
    #pragma unroll
    for (int reg = 0; reg < 16; ++reg) {
      int qq = wave * 32 + (reg & 3) + 8 * (reg >> 2) + 4 * hi;
      if (qq < SEQ)
        out[((size_t)b * SEQ + qq) * DMODEL + h * HD + d] = ov[dt][reg];
    }
  }
}

// ================== fallback: proven round-2 fused kernel ==================
#define BLK      704
#define XS_LD 136
#define WS_LD 136
#define QK_LD 72
#define PV_LD 184

struct __align__(16) SMem {
  union {
    struct {
      unsigned short Xs[SEQ * XS_LD];
      unsigned short Ws[HD  * WS_LD];
    } p1;
    unsigned short Ps[SEQ * PV_LD];
  } u;
  unsigned short Qs[SEQ * QK_LD];
  unsigned short Ks[SEQ * QK_LD];
  unsigned short Vt[HD  * PV_LD];
};

__global__ __launch_bounds__(BLK) void mha_fused_kernel(
    const float* __restrict__ x,
    const float* __restrict__ Wq, const float* __restrict__ bq,
    const float* __restrict__ Wk, const float* __restrict__ bk,
    const float* __restrict__ Wv, const float* __restrict__ bv,
    float* __restrict__ out)
{
  __shared__ SMem sm;
  const int tid  = threadIdx.x;
  const int lane = tid & 63;
  const int wave = tid >> 6;
  const int l15  = lane & 15;
  const int quad = lane >> 4;
  const int b    = blockIdx.x >> 3;
  const int h    = blockIdx.x & 7;

  const uint4 z4 = {0u, 0u, 0u, 0u};
  const bf16x8 zfrag = __builtin_bit_cast(bf16x8, z4);

  {
    const float4* xg = reinterpret_cast<const float4*>(x + (size_t)b * (SEQ * DIN));
    #pragma unroll
    for (int i = 0; i < 8; ++i) {
      int c = tid + i * BLK;
      int row  = c >> 5;
      int col4 = c & 31;
      float4 v = xg[c];
      uint2 pk;
      pk.x = (unsigned)f2bf(v.x) | ((unsigned)f2bf(v.y) << 16);
      pk.y = (unsigned)f2bf(v.z) | ((unsigned)f2bf(v.w) << 16);
      *reinterpret_cast<uint2*>(&sm.u.p1.Xs[row * XS_LD + col4 * 4]) = pk;
    }
  }

  const float* Wptr[3] = {Wq, Wk, Wv};
  const float* Bptr[3] = {bq, bk, bv};

  for (int m = 0; m < 3; ++m) {
    for (int k = wave; k < DIN; k += NMT)
      sm.u.p1.Ws[lane * WS_LD + k] = f2bf(Wptr[m][(size_t)k * DMODEL + h * HD + lane]);
    __syncthreads();

    const int mt = wave;
    bf16x8 a[4];
    #pragma unroll
    for (int kk = 0; kk < 4; ++kk)
      a[kk] = *reinterpret_cast<const bf16x8*>(
          &sm.u.p1.Xs[(mt * 16 + l15) * XS_LD + kk * 32 + quad * 8]);

    #pragma unroll
    for (int nt = 0; nt < 4; ++nt) {
      f32x4 acc = {0.f, 0.f, 0.f, 0.f};
      #pragma unroll
      for (int kk = 0; kk < 4; ++kk) {
        bf16x8 bb = *reinterpret_cast<const bf16x8*>(
            &sm.u.p1.Ws[(nt * 16 + l15) * WS_LD + kk * 32 + quad * 8]);
        acc = __builtin_amdgcn_mfma_f32_16x16x32_bf16(a[kk], bb, acc, 0, 0, 0);
      }
      float bs = Bptr[m][h * HD + nt * 16 + l15];
      if (m == 0) {
        #pragma unroll
        for (int r = 0; r < 4; ++r)
          sm.Qs[(mt * 16 + quad * 4 + r) * QK_LD + nt * 16 + l15] =
              f2bf((acc[r] + bs) * 0.125f);
      } else if (m == 1) {
        #pragma unroll
        for (int r = 0; r < 4; ++r)
          sm.Ks[(mt * 16 + quad * 4 + r) * QK_LD + nt * 16 + l15] =
              f2bf(acc[r] + bs);
      } else {
        float v0 = fmaxf(acc[0] + bs, 0.f), v1 = fmaxf(acc[1] + bs, 0.f);
        float v2 = fmaxf(acc[2] + bs, 0.f), v3 = fmaxf(acc[3] + bs, 0.f);
        uint2 pk;
        pk.x = (unsigned)f2bf(v0) | ((unsigned)f2bf(v1) << 16);
        pk.y = (unsigned)f2bf(v2) | ((unsigned)f2bf(v3) << 16);
        *reinterpret_cast<uint2*>(
            &sm.Vt[(nt * 16 + l15) * PV_LD + mt * 16 + quad * 4]) = pk;
      }
    }
    __syncthreads();
  }

  {
    const int mt = wave;
    bf16x8 aq0 = *reinterpret_cast<const bf16x8*>(
        &sm.Qs[(mt * 16 + l15) * QK_LD + 0 + quad * 8]);
    bf16x8 aq1 = *reinterpret_cast<const bf16x8*>(
        &sm.Qs[(mt * 16 + l15) * QK_LD + 32 + quad * 8]);

    f32x4 sc[NMT];
    #pragma unroll
    for (int nt = 0; nt < NMT; ++nt) {
      f32x4 acc = {0.f, 0.f, 0.f, 0.f};
      bf16x8 k0 = *reinterpret_cast<const bf16x8*>(
          &sm.Ks[(nt * 16 + l15) * QK_LD + 0 + quad * 8]);
      bf16x8 k1 = *reinterpret_cast<const bf16x8*>(
          &sm.Ks[(nt * 16 + l15) * QK_LD + 32 + quad * 8]);
      acc = __builtin_amdgcn_mfma_f32_16x16x32_bf16(aq0, k0, acc, 0, 0, 0);
      acc = __builtin_amdgcn_mfma_f32_16x16x32_bf16(aq1, k1, acc, 0, 0, 0);
      sc[nt] = acc;
    }

    float rinv[4];
    #pragma unroll
    for (int r = 0; r < 4; ++r) {
      const int q  = mt * 16 + quad * 4 + r;
      const int fq = q / JOINTS;
      float mx = -3.0e38f;
      #pragma unroll
      for (int nt = 0; nt < NMT; ++nt) {
        int c = nt * 16 + l15;
        bool masked = ((c / JOINTS) == fq) && (c != q);
        float v = masked ? -1.0e30f : sc[nt][r];
        sc[nt][r] = v;
        mx = fmaxf(mx, v);
      }
      mx = fmaxf(mx, __shfl_xor(mx, 1));
      mx = fmaxf(mx, __shfl_xor(mx, 2));
      mx = fmaxf(mx, __shfl_xor(mx, 4));
      mx = fmaxf(mx, __shfl_xor(mx, 8));
      float sum = 0.f;
      #pragma unroll
      for (int nt = 0; nt < NMT; ++nt) {
        float e = __expf(sc[nt][r] - mx);
        sum += e;
        sm.u.Ps[q * PV_LD + nt * 16 + l15] = f2bf(e);
      }
      sum += __shfl_xor(sum, 1);
      sum += __shfl_xor(sum, 2);
      sum += __shfl_xor(sum, 4);
      sum += __shfl_xor(sum, 8);
      rinv[r] = 1.0f / sum;
    }

    #pragma unroll
    for (int nt = 0; nt < 4; ++nt) {
      f32x4 acc = {0.f, 0.f, 0.f, 0.f};
      #pragma unroll
      for (int kk = 0; kk < 6; ++kk) {
        bool act = (kk < 5) || (quad < 2);
        int off = act ? (kk * 32 + quad * 8) : 0;
        bf16x8 ap  = *reinterpret_cast<const bf16x8*>(
            &sm.u.Ps[(mt * 16 + l15) * PV_LD + off]);
        bf16x8 bv8 = *reinterpret_cast<const bf16x8*>(
            &sm.Vt[(nt * 16 + l15) * PV_LD + off]);
        if (!act) { ap = zfrag; bv8 = zfrag; }
        acc = __builtin_amdgcn_mfma_f32_16x16x32_bf16(ap, bv8, acc, 0, 0, 0);
      }
      #pragma unroll
      for (int r = 0; r < 4; ++r) {
        int q = mt * 16 + quad * 4 + r;
        out[((size_t)b * SEQ + q) * DMODEL + h * HD + nt * 16 + l15] =
            acc[r] * rinv[r];
      }
    }
  }
}

// ================== launch ==================
extern "C" void kernel_launch(void* const* d_in, const int* in_sizes, int n_in,
                              void* d_out, int out_size, void* d_ws, size_t ws_size,
                              hipStream_t stream) {
  const float* x  = (const float*)d_in[0];
  const float* Wq = (const float*)d_in[1];
  const float* bq = (const float*)d_in[2];
  const float* Wk = (const float*)d_in[3];
  const float* bk = (const float*)d_in[4];
  const float* Wv = (const float*)d_in[5];
  const float* bv = (const float*)d_in[6];
  const int B = in_sizes[0] / (SEQ * DIN);   // 512

  if (ws_size >= WS_NEED && B == 512) {
    unsigned short* ws = (unsigned short*)d_ws;
    hipLaunchKernelGGL(prep_kernel, dim3(768), dim3(256), 0, stream,
                       Wq, bq, Wk, bk, Wv, bv, ws);
    hipLaunchKernelGGL(qkv_gemm_kernel, dim3(704, 4), dim3(256), 0, stream,
                       x, ws);
    hipLaunchKernelGGL(attn_kernel, dim3(4096), dim3(384), 0, stream,
                       (const unsigned short*)ws, (float*)d_out);
  } else {
    hipLaunchKernelGGL(mha_fused_kernel, dim3(B * NHEAD), dim3(BLK), 0, stream,
                       x, Wq, bq, Wk, bk, Wv, bv, (float*)d_out);
  }
}

// Round 4
// 481.995 us; speedup vs baseline: 1.2256x; 1.2256x over previous
//
#include <hip/hip_runtime.h>
#include <hip/hip_bf16.h>

#define JOINTS   22
#define SEQ      176
#define DIN      128
#define NHEAD    8
#define HD       64
#define DMODEL   512
#define NMT      11

typedef __bf16 bf16x8 __attribute__((ext_vector_type(8)));
typedef float  f32x4  __attribute__((ext_vector_type(4)));

__device__ __forceinline__ unsigned short f2bf(float f) {
  __hip_bfloat16 h = __float2bfloat16(f);
  return __builtin_bit_cast(unsigned short, h);
}
__device__ __forceinline__ float bf2f(unsigned short u) {
  __hip_bfloat16 h = __builtin_bit_cast(__hip_bfloat16, u);
  return __bfloat162float(h);
}

// ---------------- workspace layout (ushort elements) ----------------
#define WT_E    0u            // [3][512][128] bf16  W^T (Wq pre-scaled 0.125)
#define BIAS_E  196608u       // [3][512] bf16       (bq pre-scaled)
#define Q_E     198144u       // [4096][176][64] bf16
#define PERQKV  46137344u
#define K_E     (Q_E + PERQKV)
#define V_E     (K_E + PERQKV)   // [4096][64][176] bf16 (transposed, ReLU'd)
#define WS_NEED ((size_t)(V_E + PERQKV) * 2)

// ================== kernel 0: W transpose + bias prep ==================
__global__ __launch_bounds__(256) void prep_kernel(
    const float* __restrict__ Wq, const float* __restrict__ bq,
    const float* __restrict__ Wk, const float* __restrict__ bk,
    const float* __restrict__ Wv, const float* __restrict__ bv,
    unsigned short* __restrict__ ws)
{
  int idx = blockIdx.x * 256 + threadIdx.x;        // < 196608
  int which = idx >> 16;                           // 0..2
  int rem = idx & 65535;
  int n = rem >> 7, k = rem & 127;
  const float* W = (which == 0) ? Wq : (which == 1 ? Wk : Wv);
  float scale = (which == 0) ? 0.125f : 1.0f;
  ws[WT_E + idx] = f2bf(W[k * DMODEL + n] * scale);
  if (idx < 1536) {
    int w2 = idx >> 9, n2 = idx & 511;
    const float* bb = (w2 == 0) ? bq : (w2 == 1 ? bk : bv);
    float s2 = (w2 == 0) ? 0.125f : 1.0f;
    ws[BIAS_E + idx] = f2bf(bb[n2] * s2);
  }
}

// ================== kernel A: QKV projection GEMM ==================
// grid (704 m-blocks, 4 n-blocks), 256 threads. Tile 128x128, K=128.
// Epilogue v2: operand roles chosen per-matrix so the 4 r-regs are the
// contiguous store axis -> packed uint2 stores (48/thread instead of 192
// scalar), /176 hoisted (8 divisions/thread instead of 192).
__global__ __launch_bounds__(256) void qkv_gemm_kernel(
    const float* __restrict__ x, unsigned short* __restrict__ ws)
{
  __shared__ unsigned short Xs[128 * 136];
  __shared__ unsigned short Wt[128 * 136];
  const int tid  = threadIdx.x;
  const int lane = tid & 63, wave = tid >> 6;
  const int l15  = lane & 15, quad = lane >> 4;
  const int m0 = blockIdx.x * 128;
  const int nb = blockIdx.y;                        // 0..3
  const int wm = (wave >> 1) * 64, wn = (wave & 1) * 64;

  // stage X tile fp32 -> bf16 (coalesced float4)
  {
    const float4* x4 = reinterpret_cast<const float4*>(x + (size_t)m0 * DIN);
    #pragma unroll
    for (int i = 0; i < 16; ++i) {
      int c = tid + i * 256;                        // < 4096
      int row = c >> 5, col4 = c & 31;
      float4 v = x4[c];
      uint2 pk;
      pk.x = (unsigned)f2bf(v.x) | ((unsigned)f2bf(v.y) << 16);
      pk.y = (unsigned)f2bf(v.z) | ((unsigned)f2bf(v.w) << 16);
      *reinterpret_cast<uint2*>(&Xs[row * 136 + col4 * 4]) = pk;
    }
  }

  // ---- store geometry, hoisted (4-aligned groups never cross a 176 line)
  int gb[4], gs[4];   // Q/K: X-row per mt at column l15
  int vb[4], vs[4];   // V:   X-row group per mt at quad*4
  #pragma unroll
  for (int mt = 0; mt < 4; ++mt) {
    int g = m0 + wm + mt * 16 + l15;
    gb[mt] = g / 176; gs[mt] = g - gb[mt] * 176;
    int g0 = m0 + wm + mt * 16 + quad * 4;
    vb[mt] = g0 / 176; vs[mt] = g0 - vb[mt] * 176;
  }

  for (int which = 0; which < 3; ++which) {
    __syncthreads();     // protect Wt from prior-iter readers (also covers Xs)
    {
      const uint4* wsrc = reinterpret_cast<const uint4*>(
          ws + WT_E + which * 65536 + nb * 128 * 128);
      #pragma unroll
      for (int i = 0; i < 8; ++i) {
        int c = tid + i * 256;                      // < 2048
        int row = c >> 4, col8 = c & 15;
        *reinterpret_cast<uint4*>(&Wt[row * 136 + col8 * 8]) = wsrc[c];
      }
    }
    __syncthreads();

    f32x4 acc[16];
    #pragma unroll
    for (int i = 0; i < 16; ++i) acc[i] = (f32x4){0.f, 0.f, 0.f, 0.f};

    #pragma unroll
    for (int kk = 0; kk < 4; ++kk) {
      bf16x8 a[4], bfr[4];
      #pragma unroll
      for (int mt = 0; mt < 4; ++mt)
        a[mt] = *reinterpret_cast<const bf16x8*>(
            &Xs[(wm + mt * 16 + l15) * 136 + kk * 32 + quad * 8]);
      #pragma unroll
      for (int nt = 0; nt < 4; ++nt)
        bfr[nt] = *reinterpret_cast<const bf16x8*>(
            &Wt[(wn + nt * 16 + l15) * 136 + kk * 32 + quad * 8]);
      if (which != 2) {   // Q/K swapped: r-index <-> W channel (store axis d)
        #pragma unroll
        for (int mt = 0; mt < 4; ++mt)
          #pragma unroll
          for (int nt = 0; nt < 4; ++nt)
            acc[mt * 4 + nt] = __builtin_amdgcn_mfma_f32_16x16x32_bf16(
                bfr[nt], a[mt], acc[mt * 4 + nt], 0, 0, 0);
      } else {            // V unswapped: r-index <-> X row (store axis s)
        #pragma unroll
        for (int mt = 0; mt < 4; ++mt)
          #pragma unroll
          for (int nt = 0; nt < 4; ++nt)
            acc[mt * 4 + nt] = __builtin_amdgcn_mfma_f32_16x16x32_bf16(
                a[mt], bfr[nt], acc[mt * 4 + nt], 0, 0, 0);
      }
    }

    if (which != 2) {      // Q / K: store [BH][S][64], packed d-quads
      unsigned short* dst = ws + ((which == 0) ? Q_E : K_E);
      #pragma unroll
      for (int nt = 0; nt < 4; ++nt) {
        int c0 = nb * 128 + wn + nt * 16 + quad * 4;   // 4 consecutive channels
        int h = c0 >> 6, d0 = c0 & 63;
        uint2 bpk = *reinterpret_cast<const uint2*>(
            ws + BIAS_E + which * 512 + c0);
        float b0 = bf2f((unsigned short)(bpk.x & 0xffffu));
        float b1 = bf2f((unsigned short)(bpk.x >> 16));
        float b2 = bf2f((unsigned short)(bpk.y & 0xffffu));
        float b3 = bf2f((unsigned short)(bpk.y >> 16));
        #pragma unroll
        for (int mt = 0; mt < 4; ++mt) {
          f32x4 ac = acc[mt * 4 + nt];
          uint2 pk;
          pk.x = (unsigned)f2bf(ac[0] + b0) | ((unsigned)f2bf(ac[1] + b1) << 16);
          pk.y = (unsigned)f2bf(ac[2] + b2) | ((unsigned)f2bf(ac[3] + b3) << 16);
          *reinterpret_cast<uint2*>(
              &dst[((size_t)(gb[mt] * 8 + h) * 176 + gs[mt]) * 64 + d0]) = pk;
        }
      }
    } else {               // V: ReLU, store transposed [BH][64][S], packed s-quads
      unsigned short* dst = ws + V_E;
      #pragma unroll
      for (int nt = 0; nt < 4; ++nt) {
        int c = nb * 128 + wn + nt * 16 + l15;
        int h = c >> 6, d = c & 63;
        float bs = bf2f(ws[BIAS_E + 1024 + c]);
        #pragma unroll
        for (int mt = 0; mt < 4; ++mt) {
          f32x4 ac = acc[mt * 4 + nt];
          float v0 = fmaxf(ac[0] + bs, 0.f), v1 = fmaxf(ac[1] + bs, 0.f);
          float v2 = fmaxf(ac[2] + bs, 0.f), v3 = fmaxf(ac[3] + bs, 0.f);
          uint2 pk;
          pk.x = (unsigned)f2bf(v0) | ((unsigned)f2bf(v1) << 16);
          pk.y = (unsigned)f2bf(v2) | ((unsigned)f2bf(v3) << 16);
          *reinterpret_cast<uint2*>(
              &dst[((size_t)(vb[mt] * 8 + h) * 64 + d) * 176 + vs[mt]]) = pk;
        }
      }
    }
  }
}

// ================== kernel B: attention v3 (proven 181.9 us) ==================
// 4-wave block per (b,h); K/V^T staged in LDS once. QK^T computed with
// SWAPPED operands (mfma(K,Q)) so each lane owns a full P row (its l15):
// softmax = lane-local 4-wide chains + 2 shuffles, P pre-normalized and
// written packed (b64). Branch-free m-tile loop (wave 3's 12th slot is a
// dummy tile; stores guarded).
#define KLD 72     // 144B row stride: 36 dw -> 2-way max, free
#define VLD 184    // 368B: proven low-conflict
#define PLD 184

__global__ __launch_bounds__(256) void attn_kernel(
    const unsigned short* __restrict__ ws, float* __restrict__ out)
{
  __shared__ unsigned short Ks[SEQ * KLD];      // 25344 B
  __shared__ unsigned short Vt[HD * VLD];       // 23552 B
  __shared__ unsigned short Ps[4][16 * PLD];    // 23552 B

  const int tid  = threadIdx.x;
  const int lane = tid & 63, wave = tid >> 6;
  const int l15  = lane & 15, quad = lane >> 4;
  const int bh = blockIdx.x;
  const int b = bh >> 3, h = bh & 7;

  const unsigned short* qp = ws + Q_E + (size_t)bh * 11264;
  const unsigned short* kp = ws + K_E + (size_t)bh * 11264;
  const unsigned short* vp = ws + V_E + (size_t)bh * 11264;

  const uint4 z4 = {0u, 0u, 0u, 0u};
  const bf16x8 zfrag = __builtin_bit_cast(bf16x8, z4);

  // ---- Q prefetch (issues before staging loads; consumed after barrier).
  // mt may be 11 (wave 3 dummy): reads land in the K region of ws - safe.
  bf16x8 aq[3][2];
  #pragma unroll
  for (int i = 0; i < 3; ++i) {
    int mt = wave + 4 * i;
    aq[i][0] = *reinterpret_cast<const bf16x8*>(qp + (mt * 16 + l15) * 64 + quad * 8);
    aq[i][1] = *reinterpret_cast<const bf16x8*>(qp + (mt * 16 + l15) * 64 + 32 + quad * 8);
  }

  // ---- stage K: 176 rows x 8 uint4 chunks = 1408
  {
    const uint4* ks4 = reinterpret_cast<const uint4*>(kp);
    #pragma unroll
    for (int i = 0; i < 6; ++i) {
      int c = tid + i * 256;
      if (c < 1408) {
        int row = c >> 3, col = c & 7;
        *reinterpret_cast<uint4*>(&Ks[row * KLD + col * 8]) = ks4[c];
      }
    }
  }
  // ---- stage V^T: 64 rows x 22 uint4 chunks = 1408
  {
    const uint4* vs4 = reinterpret_cast<const uint4*>(vp);
    #pragma unroll
    for (int i = 0; i < 6; ++i) {
      int c = tid + i * 256;
      if (c < 1408) {
        int row = c / 22, col = c - row * 22;
        *reinterpret_cast<uint4*>(&Vt[row * VLD + col * 8]) = vs4[c];
      }
    }
  }
  __syncthreads();

  unsigned short* Pw = Ps[wave];

  #pragma unroll
  for (int i = 0; i < 3; ++i) {
    const int mt = wave + 4 * i;          // 0..11 (11 = dummy, stores guarded)

    // ---- QK^T, swapped: A = K rows (k), B = Q rows (q).
    // C[row = k_local = quad*4+r][col = q_local = l15]
    f32x4 sc[NMT];
    #pragma unroll
    for (int nt = 0; nt < NMT; ++nt) {
      bf16x8 k0 = *reinterpret_cast<const bf16x8*>(
          &Ks[(nt * 16 + l15) * KLD + quad * 8]);
      bf16x8 k1 = *reinterpret_cast<const bf16x8*>(
          &Ks[(nt * 16 + l15) * KLD + 32 + quad * 8]);
      f32x4 acc = {0.f, 0.f, 0.f, 0.f};
      acc = __builtin_amdgcn_mfma_f32_16x16x32_bf16(k0, aq[i][0], acc, 0, 0, 0);
      acc = __builtin_amdgcn_mfma_f32_16x16x32_bf16(k1, aq[i][1], acc, 0, 0, 0);
      sc[nt] = acc;
    }

    // ---- lane-local masked softmax over its own q row (q = mt*16+l15)
    const int q  = mt * 16 + l15;
    const int lo = (q / JOINTS) * JOINTS;     // frame start
    const int hi = lo + JOINTS;

    float mx0 = -3.0e38f, mx1 = -3.0e38f, mx2 = -3.0e38f, mx3 = -3.0e38f;
    #pragma unroll
    for (int nt = 0; nt < NMT; ++nt) {
      #pragma unroll
      for (int r = 0; r < 4; ++r) {
        int k = nt * 16 + quad * 4 + r;
        bool msk = (k >= lo) && (k < hi) && (k != q);
        float v = msk ? -1.0e30f : sc[nt][r];
        sc[nt][r] = v;
        if (r == 0) mx0 = fmaxf(mx0, v);
        else if (r == 1) mx1 = fmaxf(mx1, v);
        else if (r == 2) mx2 = fmaxf(mx2, v);
        else mx3 = fmaxf(mx3, v);
      }
    }
    float mx = fmaxf(fmaxf(mx0, mx1), fmaxf(mx2, mx3));
    mx = fmaxf(mx, __shfl_xor(mx, 16));
    mx = fmaxf(mx, __shfl_xor(mx, 32));

    float s0 = 0.f, s1 = 0.f, s2 = 0.f, s3 = 0.f;
    #pragma unroll
    for (int nt = 0; nt < NMT; ++nt) {
      float e0 = __expf(sc[nt][0] - mx);
      float e1 = __expf(sc[nt][1] - mx);
      float e2 = __expf(sc[nt][2] - mx);
      float e3 = __expf(sc[nt][3] - mx);
      sc[nt][0] = e0; sc[nt][1] = e1; sc[nt][2] = e2; sc[nt][3] = e3;
      s0 += e0; s1 += e1; s2 += e2; s3 += e3;
    }
    float sum = (s0 + s1) + (s2 + s3);
    sum += __shfl_xor(sum, 16);
    sum += __shfl_xor(sum, 32);
    float rinv = 1.0f / sum;

    // ---- normalize, pack 4 consecutive k per lane, b64 write (transposed):
    // Pw[row = q_local = l15][col = k = nt*16 + quad*4 + r]
    #pragma unroll
    for (int nt = 0; nt < NMT; ++nt) {
      float p0 = sc[nt][0] * rinv, p1 = sc[nt][1] * rinv;
      float p2 = sc[nt][2] * rinv, p3 = sc[nt][3] * rinv;
      uint2 pk;
      pk.x = (unsigned)f2bf(p0) | ((unsigned)f2bf(p1) << 16);
      pk.y = (unsigned)f2bf(p2) | ((unsigned)f2bf(p3) << 16);
      *reinterpret_cast<uint2*>(&Pw[l15 * PLD + nt * 16 + quad * 4]) = pk;
    }

    // ---- PV: hoist the 6 P fragments (shared across nt_o)
    bf16x8 ap[6];
    #pragma unroll
    for (int kk = 0; kk < 6; ++kk) {
      bool act = (kk < 5) || (quad < 2);
      int off = act ? (kk * 32 + quad * 8) : 0;
      bf16x8 v = *reinterpret_cast<const bf16x8*>(&Pw[l15 * PLD + off]);
      ap[kk] = act ? v : zfrag;
    }

    #pragma unroll
    for (int nt_o = 0; nt_o < 4; ++nt_o) {
      f32x4 acc = {0.f, 0.f, 0.f, 0.f};
      #pragma unroll
      for (int kk = 0; kk < 6; ++kk) {
        bool act = (kk < 5) || (quad < 2);
        int off = act ? (kk * 32 + quad * 8) : 0;
        bf16x8 bv = *reinterpret_cast<const bf16x8*>(
            &Vt[(nt_o * 16 + l15) * VLD + off]);
        acc = __builtin_amdgcn_mfma_f32_16x16x32_bf16(ap[kk], bv, acc, 0, 0, 0);
      }
      if (mt < NMT) {
        #pragma unroll
        for (int r = 0; r < 4; ++r) {
          int qq = mt * 16 + quad * 4 + r;
          out[((size_t)b * SEQ + qq) * DMODEL + h * HD + nt_o * 16 + l15] =
              acc[r];
        }
      }
    }
  }
}

// ================== fallback: proven round-2 fused kernel ==================
#define BLK      704
#define XS_LD 136
#define WS_LD 136
#define QK_LD 72
#define PV_LD 184

struct __align__(16) SMem {
  union {
    struct {
      unsigned short Xs[SEQ * XS_LD];
      unsigned short Ws[HD  * WS_LD];
    } p1;
    unsigned short Ps[SEQ * PV_LD];
  } u;
  unsigned short Qs[SEQ * QK_LD];
  unsigned short Ks[SEQ * QK_LD];
  unsigned short Vt[HD  * PV_LD];
};

__global__ __launch_bounds__(BLK) void mha_fused_kernel(
    const float* __restrict__ x,
    const float* __restrict__ Wq, const float* __restrict__ bq,
    const float* __restrict__ Wk, const float* __restrict__ bk,
    const float* __restrict__ Wv, const float* __restrict__ bv,
    float* __restrict__ out)
{
  __shared__ SMem sm;
  const int tid  = threadIdx.x;
  const int lane = tid & 63;
  const int wave = tid >> 6;
  const int l15  = lane & 15;
  const int quad = lane >> 4;
  const int b    = blockIdx.x >> 3;
  const int h    = blockIdx.x & 7;

  const uint4 z4 = {0u, 0u, 0u, 0u};
  const bf16x8 zfrag = __builtin_bit_cast(bf16x8, z4);

  {
    const float4* xg = reinterpret_cast<const float4*>(x + (size_t)b * (SEQ * DIN));
    #pragma unroll
    for (int i = 0; i < 8; ++i) {
      int c = tid + i * BLK;
      int row  = c >> 5;
      int col4 = c & 31;
      float4 v = xg[c];
      uint2 pk;
      pk.x = (unsigned)f2bf(v.x) | ((unsigned)f2bf(v.y) << 16);
      pk.y = (unsigned)f2bf(v.z) | ((unsigned)f2bf(v.w) << 16);
      *reinterpret_cast<uint2*>(&sm.u.p1.Xs[row * XS_LD + col4 * 4]) = pk;
    }
  }

  const float* Wptr[3] = {Wq, Wk, Wv};
  const float* Bptr[3] = {bq, bk, bv};

  for (int m = 0; m < 3; ++m) {
    for (int k = wave; k < DIN; k += NMT)
      sm.u.p1.Ws[lane * WS_LD + k] = f2bf(Wptr[m][(size_t)k * DMODEL + h * HD + lane]);
    __syncthreads();

    const int mt = wave;
    bf16x8 a[4];
    #pragma unroll
    for (int kk = 0; kk < 4; ++kk)
      a[kk] = *reinterpret_cast<const bf16x8*>(
          &sm.u.p1.Xs[(mt * 16 + l15) * XS_LD + kk * 32 + quad * 8]);

    #pragma unroll
    for (int nt = 0; nt < 4; ++nt) {
      f32x4 acc = {0.f, 0.f, 0.f, 0.f};
      #pragma unroll
      for (int kk = 0; kk < 4; ++kk) {
        bf16x8 bb = *reinterpret_cast<const bf16x8*>(
            &sm.u.p1.Ws[(nt * 16 + l15) * WS_LD + kk * 32 + quad * 8]);
        acc = __builtin_amdgcn_mfma_f32_16x16x32_bf16(a[kk], bb, acc, 0, 0, 0);
      }
      float bs = Bptr[m][h * HD + nt * 16 + l15];
      if (m == 0) {
        #pragma unroll
        for (int r = 0; r < 4; ++r)
          sm.Qs[(mt * 16 + quad * 4 + r) * QK_LD + nt * 16 + l15] =
              f2bf((acc[r] + bs) * 0.125f);
      } else if (m == 1) {
        #pragma unroll
        for (int r = 0; r < 4; ++r)
          sm.Ks[(mt * 16 + quad * 4 + r) * QK_LD + nt * 16 + l15] =
              f2bf(acc[r] + bs);
      } else {
        float v0 = fmaxf(acc[0] + bs, 0.f), v1 = fmaxf(acc[1] + bs, 0.f);
        float v2 = fmaxf(acc[2] + bs, 0.f), v3 = fmaxf(acc[3] + bs, 0.f);
        uint2 pk;
        pk.x = (unsigned)f2bf(v0) | ((unsigned)f2bf(v1) << 16);
        pk.y = (unsigned)f2bf(v2) | ((unsigned)f2bf(v3) << 16);
        *reinterpret_cast<uint2*>(
            &sm.Vt[(nt * 16 + l15) * PV_LD + mt * 16 + quad * 4]) = pk;
      }
    }
    __syncthreads();
  }

  {
    const int mt = wave;
    bf16x8 aq0 = *reinterpret_cast<const bf16x8*>(
        &sm.Qs[(mt * 16 + l15) * QK_LD + 0 + quad * 8]);
    bf16x8 aq1 = *reinterpret_cast<const bf16x8*>(
        &sm.Qs[(mt * 16 + l15) * QK_LD + 32 + quad * 8]);

    f32x4 sc[NMT];
    #pragma unroll
    for (int nt = 0; nt < NMT; ++nt) {
      f32x4 acc = {0.f, 0.f, 0.f, 0.f};
      bf16x8 k0 = *reinterpret_cast<const bf16x8*>(
          &sm.Ks[(nt * 16 + l15) * QK_LD + 0 + quad * 8]);
      bf16x8 k1 = *reinterpret_cast<const bf16x8*>(
          &sm.Ks[(nt * 16 + l15) * QK_LD + 32 + quad * 8]);
      acc = __builtin_amdgcn_mfma_f32_16x16x32_bf16(aq0, k0, acc, 0, 0, 0);
      acc = __builtin_amdgcn_mfma_f32_16x16x32_bf16(aq1, k1, acc, 0, 0, 0);
      sc[nt] = acc;
    }

    float rinv[4];
    #pragma unroll
    for (int r = 0; r < 4; ++r) {
      const int q  = mt * 16 + quad * 4 + r;
      const int fq = q / JOINTS;
      float mx = -3.0e38f;
      #pragma unroll
      for (int nt = 0; nt < NMT; ++nt) {
        int c = nt * 16 + l15;
        bool masked = ((c / JOINTS) == fq) && (c != q);
        float v = masked ? -1.0e30f : sc[nt][r];
        sc[nt][r] = v;
        mx = fmaxf(mx, v);
      }
      mx = fmaxf(mx, __shfl_xor(mx, 1));
      mx = fmaxf(mx, __shfl_xor(mx, 2));
      mx = fmaxf(mx, __shfl_xor(mx, 4));
      mx = fmaxf(mx, __shfl_xor(mx, 8));
      float sum = 0.f;
      #pragma unroll
      for (int nt = 0; nt < NMT; ++nt) {
        float e = __expf(sc[nt][r] - mx);
        sum += e;
        sm.u.Ps[q * PV_LD + nt * 16 + l15] = f2bf(e);
      }
      sum += __shfl_xor(sum, 1);
      sum += __shfl_xor(sum, 2);
      sum += __shfl_xor(sum, 4);
      sum += __shfl_xor(sum, 8);
      rinv[r] = 1.0f / sum;
    }

    #pragma unroll
    for (int nt = 0; nt < 4; ++nt) {
      f32x4 acc = {0.f, 0.f, 0.f, 0.f};
      #pragma unroll
      for (int kk = 0; kk < 6; ++kk) {
        bool act = (kk < 5) || (quad < 2);
        int off = act ? (kk * 32 + quad * 8) : 0;
        bf16x8 ap  = *reinterpret_cast<const bf16x8*>(
            &sm.u.Ps[(mt * 16 + l15) * PV_LD + off]);
        bf16x8 bv8 = *reinterpret_cast<const bf16x8*>(
            &sm.Vt[(nt * 16 + l15) * PV_LD + off]);
        if (!act) { ap = zfrag; bv8 = zfrag; }
        acc = __builtin_amdgcn_mfma_f32_16x16x32_bf16(ap, bv8, acc, 0, 0, 0);
      }
      #pragma unroll
      for (int r = 0; r < 4; ++r) {
        int q = mt * 16 + quad * 4 + r;
        out[((size_t)b * SEQ + q) * DMODEL + h * HD + nt * 16 + l15] =
            acc[r] * rinv[r];
      }
    }
  }
}

// ================== launch ==================
extern "C" void kernel_launch(void* const* d_in, const int* in_sizes, int n_in,
                              void* d_out, int out_size, void* d_ws, size_t ws_size,
                              hipStream_t stream) {
  const float* x  = (const float*)d_in[0];
  const float* Wq = (const float*)d_in[1];
  const float* bq = (const float*)d_in[2];
  const float* Wk = (const float*)d_in[3];
  const float* bk = (const float*)d_in[4];
  const float* Wv = (const float*)d_in[5];
  const float* bv = (const float*)d_in[6];
  const int B = in_sizes[0] / (SEQ * DIN);   // 512

  if (ws_size >= WS_NEED && B == 512) {
    unsigned short* ws = (unsigned short*)d_ws;
    hipLaunchKernelGGL(prep_kernel, dim3(768), dim3(256), 0, stream,
                       Wq, bq, Wk, bk, Wv, bv, ws);
    hipLaunchKernelGGL(qkv_gemm_kernel, dim3(704, 4), dim3(256), 0, stream,
                       x, ws);
    hipLaunchKernelGGL(attn_kernel, dim3(4096), dim3(256), 0, stream,
                       (const unsigned short*)ws, (float*)d_out);
  } else {
    hipLaunchKernelGGL(mha_fused_kernel, dim3(B * NHEAD), dim3(BLK), 0, stream,
                       x, Wq, bq, Wk, bk, Wv, bv, (float*)d_out);
  }
}

// Round 5
// 459.114 us; speedup vs baseline: 1.2867x; 1.0498x over previous
//
#include <hip/hip_runtime.h>
#include <hip/hip_bf16.h>

#define JOINTS   22
#define SEQ      176
#define DIN      128
#define NHEAD    8
#define HD       64
#define DMODEL   512
#define NMT      11

typedef __bf16 bf16x8 __attribute__((ext_vector_type(8)));
typedef float  f32x4  __attribute__((ext_vector_type(4)));

__device__ __forceinline__ unsigned short f2bf(float f) {
  __hip_bfloat16 h = __float2bfloat16(f);
  return __builtin_bit_cast(unsigned short, h);
}
__device__ __forceinline__ float bf2f(unsigned short u) {
  __hip_bfloat16 h = __builtin_bit_cast(__hip_bfloat16, u);
  return __bfloat162float(h);
}

// ---------------- workspace layout (ushort elements) ----------------
#define WT_E    0u            // [3][512][128] bf16  W^T (Wq pre-scaled 0.125)
#define BIAS_E  196608u       // [3][512] bf16       (bq pre-scaled)
#define Q_E     198144u       // [4096][176][64] bf16
#define PERQKV  46137344u
#define K_E     (Q_E + PERQKV)
#define V_E     (K_E + PERQKV)   // [4096][64][176] bf16 (transposed, ReLU'd)
#define WS_NEED ((size_t)(V_E + PERQKV) * 2)

// ================== kernel 0: W transpose + bias prep ==================
__global__ __launch_bounds__(256) void prep_kernel(
    const float* __restrict__ Wq, const float* __restrict__ bq,
    const float* __restrict__ Wk, const float* __restrict__ bk,
    const float* __restrict__ Wv, const float* __restrict__ bv,
    unsigned short* __restrict__ ws)
{
  int idx = blockIdx.x * 256 + threadIdx.x;        // < 196608
  int which = idx >> 16;                           // 0..2
  int rem = idx & 65535;
  int n = rem >> 7, k = rem & 127;
  const float* W = (which == 0) ? Wq : (which == 1 ? Wk : Wv);
  float scale = (which == 0) ? 0.125f : 1.0f;
  ws[WT_E + idx] = f2bf(W[k * DMODEL + n] * scale);
  if (idx < 1536) {
    int w2 = idx >> 9, n2 = idx & 511;
    const float* bb = (w2 == 0) ? bq : (w2 == 1 ? bk : bv);
    float s2 = (w2 == 0) ? 0.125f : 1.0f;
    ws[BIAS_E + idx] = f2bf(bb[n2] * s2);
  }
}

// ================== kernel A: QKV projection GEMM ==================
// grid (704 m-blocks, 4 n-blocks), 256 threads. Tile 128x128, K=128.
// Epilogue v2: operand roles chosen per-matrix so the 4 r-regs are the
// contiguous store axis -> packed uint2 stores, /176 hoisted.
__global__ __launch_bounds__(256) void qkv_gemm_kernel(
    const float* __restrict__ x, unsigned short* __restrict__ ws)
{
  __shared__ unsigned short Xs[128 * 136];
  __shared__ unsigned short Wt[128 * 136];
  const int tid  = threadIdx.x;
  const int lane = tid & 63, wave = tid >> 6;
  const int l15  = lane & 15, quad = lane >> 4;
  const int m0 = blockIdx.x * 128;
  const int nb = blockIdx.y;                        // 0..3
  const int wm = (wave >> 1) * 64, wn = (wave & 1) * 64;

  // stage X tile fp32 -> bf16 (coalesced float4)
  {
    const float4* x4 = reinterpret_cast<const float4*>(x + (size_t)m0 * DIN);
    #pragma unroll
    for (int i = 0; i < 16; ++i) {
      int c = tid + i * 256;                        // < 4096
      int row = c >> 5, col4 = c & 31;
      float4 v = x4[c];
      uint2 pk;
      pk.x = (unsigned)f2bf(v.x) | ((unsigned)f2bf(v.y) << 16);
      pk.y = (unsigned)f2bf(v.z) | ((unsigned)f2bf(v.w) << 16);
      *reinterpret_cast<uint2*>(&Xs[row * 136 + col4 * 4]) = pk;
    }
  }

  // ---- store geometry, hoisted (4-aligned groups never cross a 176 line)
  int gb[4], gs[4];   // Q/K: X-row per mt at column l15
  int vb[4], vs[4];   // V:   X-row group per mt at quad*4
  #pragma unroll
  for (int mt = 0; mt < 4; ++mt) {
    int g = m0 + wm + mt * 16 + l15;
    gb[mt] = g / 176; gs[mt] = g - gb[mt] * 176;
    int g0 = m0 + wm + mt * 16 + quad * 4;
    vb[mt] = g0 / 176; vs[mt] = g0 - vb[mt] * 176;
  }

  for (int which = 0; which < 3; ++which) {
    __syncthreads();     // protect Wt from prior-iter readers (also covers Xs)
    {
      const uint4* wsrc = reinterpret_cast<const uint4*>(
          ws + WT_E + which * 65536 + nb * 128 * 128);
      #pragma unroll
      for (int i = 0; i < 8; ++i) {
        int c = tid + i * 256;                      // < 2048
        int row = c >> 4, col8 = c & 15;
        *reinterpret_cast<uint4*>(&Wt[row * 136 + col8 * 8]) = wsrc[c];
      }
    }
    __syncthreads();

    f32x4 acc[16];
    #pragma unroll
    for (int i = 0; i < 16; ++i) acc[i] = (f32x4){0.f, 0.f, 0.f, 0.f};

    #pragma unroll
    for (int kk = 0; kk < 4; ++kk) {
      bf16x8 a[4], bfr[4];
      #pragma unroll
      for (int mt = 0; mt < 4; ++mt)
        a[mt] = *reinterpret_cast<const bf16x8*>(
            &Xs[(wm + mt * 16 + l15) * 136 + kk * 32 + quad * 8]);
      #pragma unroll
      for (int nt = 0; nt < 4; ++nt)
        bfr[nt] = *reinterpret_cast<const bf16x8*>(
            &Wt[(wn + nt * 16 + l15) * 136 + kk * 32 + quad * 8]);
      if (which != 2) {   // Q/K swapped: r-index <-> W channel (store axis d)
        #pragma unroll
        for (int mt = 0; mt < 4; ++mt)
          #pragma unroll
          for (int nt = 0; nt < 4; ++nt)
            acc[mt * 4 + nt] = __builtin_amdgcn_mfma_f32_16x16x32_bf16(
                bfr[nt], a[mt], acc[mt * 4 + nt], 0, 0, 0);
      } else {            // V unswapped: r-index <-> X row (store axis s)
        #pragma unroll
        for (int mt = 0; mt < 4; ++mt)
          #pragma unroll
          for (int nt = 0; nt < 4; ++nt)
            acc[mt * 4 + nt] = __builtin_amdgcn_mfma_f32_16x16x32_bf16(
                a[mt], bfr[nt], acc[mt * 4 + nt], 0, 0, 0);
      }
    }

    if (which != 2) {      // Q / K: store [BH][S][64], packed d-quads
      unsigned short* dst = ws + ((which == 0) ? Q_E : K_E);
      #pragma unroll
      for (int nt = 0; nt < 4; ++nt) {
        int c0 = nb * 128 + wn + nt * 16 + quad * 4;   // 4 consecutive channels
        int h = c0 >> 6, d0 = c0 & 63;
        uint2 bpk = *reinterpret_cast<const uint2*>(
            ws + BIAS_E + which * 512 + c0);
        float b0 = bf2f((unsigned short)(bpk.x & 0xffffu));
        float b1 = bf2f((unsigned short)(bpk.x >> 16));
        float b2 = bf2f((unsigned short)(bpk.y & 0xffffu));
        float b3 = bf2f((unsigned short)(bpk.y >> 16));
        #pragma unroll
        for (int mt = 0; mt < 4; ++mt) {
          f32x4 ac = acc[mt * 4 + nt];
          uint2 pk;
          pk.x = (unsigned)f2bf(ac[0] + b0) | ((unsigned)f2bf(ac[1] + b1) << 16);
          pk.y = (unsigned)f2bf(ac[2] + b2) | ((unsigned)f2bf(ac[3] + b3) << 16);
          *reinterpret_cast<uint2*>(
              &dst[((size_t)(gb[mt] * 8 + h) * 176 + gs[mt]) * 64 + d0]) = pk;
        }
      }
    } else {               // V: ReLU, store transposed [BH][64][S], packed s-quads
      unsigned short* dst = ws + V_E;
      #pragma unroll
      for (int nt = 0; nt < 4; ++nt) {
        int c = nb * 128 + wn + nt * 16 + l15;
        int h = c >> 6, d = c & 63;
        float bs = bf2f(ws[BIAS_E + 1024 + c]);
        #pragma unroll
        for (int mt = 0; mt < 4; ++mt) {
          f32x4 ac = acc[mt * 4 + nt];
          float v0 = fmaxf(ac[0] + bs, 0.f), v1 = fmaxf(ac[1] + bs, 0.f);
          float v2 = fmaxf(ac[2] + bs, 0.f), v3 = fmaxf(ac[3] + bs, 0.f);
          uint2 pk;
          pk.x = (unsigned)f2bf(v0) | ((unsigned)f2bf(v1) << 16);
          pk.y = (unsigned)f2bf(v2) | ((unsigned)f2bf(v3) << 16);
          *reinterpret_cast<uint2*>(
              &dst[((size_t)(vb[mt] * 8 + h) * 64 + d) * 176 + vs[mt]]) = pk;
        }
      }
    }
  }
}

// ================== kernel B: attention v5 (register-P, no Ps buffer) ====
// 4-wave block per (b,h); K/V^T staged in LDS once. Swapped QK^T (mfma(K,Q))
// puts P[q=mt*16+l15][k=nt*16+quad*4+r] in registers. PV feeds those regs
// directly as the A-operand in their NATURAL k-order by pairing tiles
// (ntA,ntB) into one bf16x8 and reading V's B-operand at the SAME permuted
// k-offsets (two ds_read_b64 at ntA*16+quad*4 / ntB*16+quad*4). MFMA
// contraction is positional, so a shared injective k-permutation is exact.
// Deletes the Ps buffer: LDS 72.7->47.8 KB => 3 blocks/CU (12 waves).
#define KLD 72     // 144B row stride: conflict-free for b128 QK reads
#define VLD 184    // 368B: b64 PV reads land 4 accesses/bank = wave64 min

__global__ __launch_bounds__(256, 3) void attn_kernel(
    const unsigned short* __restrict__ ws, float* __restrict__ out)
{
  __shared__ unsigned short Ks[SEQ * KLD];      // 25344 B
  __shared__ unsigned short Vt[HD * VLD];       // 23552 B  (48896 B total)

  const int tid  = threadIdx.x;
  const int lane = tid & 63, wave = tid >> 6;
  const int l15  = lane & 15, quad = lane >> 4;
  const int bh = blockIdx.x;
  const int b = bh >> 3, h = bh & 7;

  const unsigned short* qp = ws + Q_E + (size_t)bh * 11264;
  const unsigned short* kp = ws + K_E + (size_t)bh * 11264;
  const unsigned short* vp = ws + V_E + (size_t)bh * 11264;

  // ---- Q prefetch (issues before staging loads; consumed after barrier).
  // mt may be 11 (wave 3 dummy): reads land in adjacent ws regions - safe.
  bf16x8 aq[3][2];
  #pragma unroll
  for (int i = 0; i < 3; ++i) {
    int mt = wave + 4 * i;
    aq[i][0] = *reinterpret_cast<const bf16x8*>(qp + (mt * 16 + l15) * 64 + quad * 8);
    aq[i][1] = *reinterpret_cast<const bf16x8*>(qp + (mt * 16 + l15) * 64 + 32 + quad * 8);
  }

  // ---- stage K: 176 rows x 8 uint4 chunks = 1408
  {
    const uint4* ks4 = reinterpret_cast<const uint4*>(kp);
    #pragma unroll
    for (int i = 0; i < 6; ++i) {
      int c = tid + i * 256;
      if (c < 1408) {
        int row = c >> 3, col = c & 7;
        *reinterpret_cast<uint4*>(&Ks[row * KLD + col * 8]) = ks4[c];
      }
    }
  }
  // ---- stage V^T: 64 rows x 22 uint4 chunks = 1408
  {
    const uint4* vs4 = reinterpret_cast<const uint4*>(vp);
    #pragma unroll
    for (int i = 0; i < 6; ++i) {
      int c = tid + i * 256;
      if (c < 1408) {
        int row = c / 22, col = c - row * 22;
        *reinterpret_cast<uint4*>(&Vt[row * VLD + col * 8]) = vs4[c];
      }
    }
  }
  __syncthreads();

  #pragma unroll
  for (int i = 0; i < 3; ++i) {
    const int mt = wave + 4 * i;          // 0..11 (11 = dummy, stores guarded)

    // ---- QK^T, swapped: A = K rows (k), B = Q rows (q).
    // sc[nt] lane (l15,quad): S[q=mt*16+l15][k=nt*16+quad*4+r]
    f32x4 sc[NMT];
    #pragma unroll
    for (int nt = 0; nt < NMT; ++nt) {
      bf16x8 k0 = *reinterpret_cast<const bf16x8*>(
          &Ks[(nt * 16 + l15) * KLD + quad * 8]);
      bf16x8 k1 = *reinterpret_cast<const bf16x8*>(
          &Ks[(nt * 16 + l15) * KLD + 32 + quad * 8]);
      f32x4 acc = {0.f, 0.f, 0.f, 0.f};
      acc = __builtin_amdgcn_mfma_f32_16x16x32_bf16(k0, aq[i][0], acc, 0, 0, 0);
      acc = __builtin_amdgcn_mfma_f32_16x16x32_bf16(k1, aq[i][1], acc, 0, 0, 0);
      sc[nt] = acc;
    }

    // ---- lane-local masked softmax over its own q row (q = mt*16+l15)
    const int q  = mt * 16 + l15;
    const int lo = (q / JOINTS) * JOINTS;     // frame start
    const int hi = lo + JOINTS;

    float mx0 = -3.0e38f, mx1 = -3.0e38f, mx2 = -3.0e38f, mx3 = -3.0e38f;
    #pragma unroll
    for (int nt = 0; nt < NMT; ++nt) {
      #pragma unroll
      for (int r = 0; r < 4; ++r) {
        int k = nt * 16 + quad * 4 + r;
        bool msk = (k >= lo) && (k < hi) && (k != q);
        float v = msk ? -1.0e30f : sc[nt][r];
        sc[nt][r] = v;
        if (r == 0) mx0 = fmaxf(mx0, v);
        else if (r == 1) mx1 = fmaxf(mx1, v);
        else if (r == 2) mx2 = fmaxf(mx2, v);
        else mx3 = fmaxf(mx3, v);
      }
    }
    float mx = fmaxf(fmaxf(mx0, mx1), fmaxf(mx2, mx3));
    mx = fmaxf(mx, __shfl_xor(mx, 16));
    mx = fmaxf(mx, __shfl_xor(mx, 32));

    float s0 = 0.f, s1 = 0.f, s2 = 0.f, s3 = 0.f;
    #pragma unroll
    for (int nt = 0; nt < NMT; ++nt) {
      float e0 = __expf(sc[nt][0] - mx);
      float e1 = __expf(sc[nt][1] - mx);
      float e2 = __expf(sc[nt][2] - mx);
      float e3 = __expf(sc[nt][3] - mx);
      sc[nt][0] = e0; sc[nt][1] = e1; sc[nt][2] = e2; sc[nt][3] = e3;
      s0 += e0; s1 += e1; s2 += e2; s3 += e3;
    }
    float sum = (s0 + s1) + (s2 + s3);
    sum += __shfl_xor(sum, 16);
    sum += __shfl_xor(sum, 32);
    float rinv = 1.0f / sum;

    // ---- normalize + pack pairs (ntA,ntB) -> A-fragments in natural order
    // af[pr] elems: [P@2pr*16+quad*4+0..3, P@(2pr+1)*16+quad*4+0..3]
    bf16x8 af[6];
    #pragma unroll
    for (int pr = 0; pr < 6; ++pr) {
      const int ntA = 2 * pr, ntB = 2 * pr + 1;
      uint4 a4;
      {
        float p0 = sc[ntA][0] * rinv, p1 = sc[ntA][1] * rinv;
        float p2 = sc[ntA][2] * rinv, p3 = sc[ntA][3] * rinv;
        a4.x = (unsigned)f2bf(p0) | ((unsigned)f2bf(p1) << 16);
        a4.y = (unsigned)f2bf(p2) | ((unsigned)f2bf(p3) << 16);
      }
      if (pr < 5) {
        float p0 = sc[ntB][0] * rinv, p1 = sc[ntB][1] * rinv;
        float p2 = sc[ntB][2] * rinv, p3 = sc[ntB][3] * rinv;
        a4.z = (unsigned)f2bf(p0) | ((unsigned)f2bf(p1) << 16);
        a4.w = (unsigned)f2bf(p2) | ((unsigned)f2bf(p3) << 16);
      } else {
        a4.z = 0u; a4.w = 0u;            // pad half: contributes 0
      }
      af[pr] = __builtin_bit_cast(bf16x8, a4);
    }

    // ---- PV: B-operand read at the SAME permuted k-offsets (two b64)
    #pragma unroll
    for (int nt_o = 0; nt_o < 4; ++nt_o) {
      const unsigned short* vrow = &Vt[(nt_o * 16 + l15) * VLD];
      f32x4 acc = {0.f, 0.f, 0.f, 0.f};
      #pragma unroll
      for (int pr = 0; pr < 6; ++pr) {
        const int ntA = 2 * pr, ntB = 2 * pr + 1;
        uint2 blo = *reinterpret_cast<const uint2*>(vrow + ntA * 16 + quad * 4);
        uint2 bhi = (pr < 5)
            ? *reinterpret_cast<const uint2*>(vrow + ntB * 16 + quad * 4)
            : (uint2){0u, 0u};
        uint4 b4; b4.x = blo.x; b4.y = blo.y; b4.z = bhi.x; b4.w = bhi.y;
        bf16x8 bf = __builtin_bit_cast(bf16x8, b4);
        acc = __builtin_amdgcn_mfma_f32_16x16x32_bf16(af[pr], bf, acc, 0, 0, 0);
      }
      if (mt < NMT) {
        #pragma unroll
        for (int r = 0; r < 4; ++r) {
          int qq = mt * 16 + quad * 4 + r;
          out[((size_t)b * SEQ + qq) * DMODEL + h * HD + nt_o * 16 + l15] =
              acc[r];
        }
      }
    }
  }
}

// ================== fallback: proven round-2 fused kernel ==================
#define BLK      704
#define XS_LD 136
#define WS_LD 136
#define QK_LD 72
#define PV_LD 184

struct __align__(16) SMem {
  union {
    struct {
      unsigned short Xs[SEQ * XS_LD];
      unsigned short Ws[HD  * WS_LD];
    } p1;
    unsigned short Ps[SEQ * PV_LD];
  } u;
  unsigned short Qs[SEQ * QK_LD];
  unsigned short Ks[SEQ * QK_LD];
  unsigned short Vt[HD  * PV_LD];
};

__global__ __launch_bounds__(BLK) void mha_fused_kernel(
    const float* __restrict__ x,
    const float* __restrict__ Wq, const float* __restrict__ bq,
    const float* __restrict__ Wk, const float* __restrict__ bk,
    const float* __restrict__ Wv, const float* __restrict__ bv,
    float* __restrict__ out)
{
  __shared__ SMem sm;
  const int tid  = threadIdx.x;
  const int lane = tid & 63;
  const int wave = tid >> 6;
  const int l15  = lane & 15;
  const int quad = lane >> 4;
  const int b    = blockIdx.x >> 3;
  const int h    = blockIdx.x & 7;

  const uint4 z4 = {0u, 0u, 0u, 0u};
  const bf16x8 zfrag = __builtin_bit_cast(bf16x8, z4);

  {
    const float4* xg = reinterpret_cast<const float4*>(x + (size_t)b * (SEQ * DIN));
    #pragma unroll
    for (int i = 0; i < 8; ++i) {
      int c = tid + i * BLK;
      int row  = c >> 5;
      int col4 = c & 31;
      float4 v = xg[c];
      uint2 pk;
      pk.x = (unsigned)f2bf(v.x) | ((unsigned)f2bf(v.y) << 16);
      pk.y = (unsigned)f2bf(v.z) | ((unsigned)f2bf(v.w) << 16);
      *reinterpret_cast<uint2*>(&sm.u.p1.Xs[row * XS_LD + col4 * 4]) = pk;
    }
  }

  const float* Wptr[3] = {Wq, Wk, Wv};
  const float* Bptr[3] = {bq, bk, bv};

  for (int m = 0; m < 3; ++m) {
    for (int k = wave; k < DIN; k += NMT)
      sm.u.p1.Ws[lane * WS_LD + k] = f2bf(Wptr[m][(size_t)k * DMODEL + h * HD + lane]);
    __syncthreads();

    const int mt = wave;
    bf16x8 a[4];
    #pragma unroll
    for (int kk = 0; kk < 4; ++kk)
      a[kk] = *reinterpret_cast<const bf16x8*>(
          &sm.u.p1.Xs[(mt * 16 + l15) * XS_LD + kk * 32 + quad * 8]);

    #pragma unroll
    for (int nt = 0; nt < 4; ++nt) {
      f32x4 acc = {0.f, 0.f, 0.f, 0.f};
      #pragma unroll
      for (int kk = 0; kk < 4; ++kk) {
        bf16x8 bb = *reinterpret_cast<const bf16x8*>(
            &sm.u.p1.Ws[(nt * 16 + l15) * WS_LD + kk * 32 + quad * 8]);
        acc = __builtin_amdgcn_mfma_f32_16x16x32_bf16(a[kk], bb, acc, 0, 0, 0);
      }
      float bs = Bptr[m][h * HD + nt * 16 + l15];
      if (m == 0) {
        #pragma unroll
        for (int r = 0; r < 4; ++r)
          sm.Qs[(mt * 16 + quad * 4 + r) * QK_LD + nt * 16 + l15] =
              f2bf((acc[r] + bs) * 0.125f);
      } else if (m == 1) {
        #pragma unroll
        for (int r = 0; r < 4; ++r)
          sm.Ks[(mt * 16 + quad * 4 + r) * QK_LD + nt * 16 + l15] =
              f2bf(acc[r] + bs);
      } else {
        float v0 = fmaxf(acc[0] + bs, 0.f), v1 = fmaxf(acc[1] + bs, 0.f);
        float v2 = fmaxf(acc[2] + bs, 0.f), v3 = fmaxf(acc[3] + bs, 0.f);
        uint2 pk;
        pk.x = (unsigned)f2bf(v0) | ((unsigned)f2bf(v1) << 16);
        pk.y = (unsigned)f2bf(v2) | ((unsigned)f2bf(v3) << 16);
        *reinterpret_cast<uint2*>(
            &sm.Vt[(nt * 16 + l15) * PV_LD + mt * 16 + quad * 4]) = pk;
      }
    }
    __syncthreads();
  }

  {
    const int mt = wave;
    bf16x8 aq0 = *reinterpret_cast<const bf16x8*>(
        &sm.Qs[(mt * 16 + l15) * QK_LD + 0 + quad * 8]);
    bf16x8 aq1 = *reinterpret_cast<const bf16x8*>(
        &sm.Qs[(mt * 16 + l15) * QK_LD + 32 + quad * 8]);

    f32x4 sc[NMT];
    #pragma unroll
    for (int nt = 0; nt < NMT; ++nt) {
      f32x4 acc = {0.f, 0.f, 0.f, 0.f};
      bf16x8 k0 = *reinterpret_cast<const bf16x8*>(
          &sm.Ks[(nt * 16 + l15) * QK_LD + 0 + quad * 8]);
      bf16x8 k1 = *reinterpret_cast<const bf16x8*>(
          &sm.Ks[(nt * 16 + l15) * QK_LD + 32 + quad * 8]);
      acc = __builtin_amdgcn_mfma_f32_16x16x32_bf16(aq0, k0, acc, 0, 0, 0);
      acc = __builtin_amdgcn_mfma_f32_16x16x32_bf16(aq1, k1, acc, 0, 0, 0);
      sc[nt] = acc;
    }

    float rinv[4];
    #pragma unroll
    for (int r = 0; r < 4; ++r) {
      const int q  = mt * 16 + quad * 4 + r;
      const int fq = q / JOINTS;
      float mx = -3.0e38f;
      #pragma unroll
      for (int nt = 0; nt < NMT; ++nt) {
        int c = nt * 16 + l15;
        bool masked = ((c / JOINTS) == fq) && (c != q);
        float v = masked ? -1.0e30f : sc[nt][r];
        sc[nt][r] = v;
        mx = fmaxf(mx, v);
      }
      mx = fmaxf(mx, __shfl_xor(mx, 1));
      mx = fmaxf(mx, __shfl_xor(mx, 2));
      mx = fmaxf(mx, __shfl_xor(mx, 4));
      mx = fmaxf(mx, __shfl_xor(mx, 8));
      float sum = 0.f;
      #pragma unroll
      for (int nt = 0; nt < NMT; ++nt) {
        float e = __expf(sc[nt][r] - mx);
        sum += e;
        sm.u.Ps[q * PV_LD + nt * 16 + l15] = f2bf(e);
      }
      sum += __shfl_xor(sum, 1);
      sum += __shfl_xor(sum, 2);
      sum += __shfl_xor(sum, 4);
      sum += __shfl_xor(sum, 8);
      rinv[r] = 1.0f / sum;
    }

    #pragma unroll
    for (int nt = 0; nt < 4; ++nt) {
      f32x4 acc = {0.f, 0.f, 0.f, 0.f};
      #pragma unroll
      for (int kk = 0; kk < 6; ++kk) {
        bool act = (kk < 5) || (quad < 2);
        int off = act ? (kk * 32 + quad * 8) : 0;
        bf16x8 ap  = *reinterpret_cast<const bf16x8*>(
            &sm.u.Ps[(mt * 16 + l15) * PV_LD + off]);
        bf16x8 bv8 = *reinterpret_cast<const bf16x8*>(
            &sm.Vt[(nt * 16 + l15) * PV_LD + off]);
        if (!act) { ap = zfrag; bv8 = zfrag; }
        acc = __builtin_amdgcn_mfma_f32_16x16x32_bf16(ap, bv8, acc, 0, 0, 0);
      }
      #pragma unroll
      for (int r = 0; r < 4; ++r) {
        int q = mt * 16 + quad * 4 + r;
        out[((size_t)b * SEQ + q) * DMODEL + h * HD + nt * 16 + l15] =
            acc[r] * rinv[r];
      }
    }
  }
}

// ================== launch ==================
extern "C" void kernel_launch(void* const* d_in, const int* in_sizes, int n_in,
                              void* d_out, int out_size, void* d_ws, size_t ws_size,
                              hipStream_t stream) {
  const float* x  = (const float*)d_in[0];
  const float* Wq = (const float*)d_in[1];
  const float* bq = (const float*)d_in[2];
  const float* Wk = (const float*)d_in[3];
  const float* bk = (const float*)d_in[4];
  const float* Wv = (const float*)d_in[5];
  const float* bv = (const float*)d_in[6];
  const int B = in_sizes[0] / (SEQ * DIN);   // 512

  if (ws_size >= WS_NEED && B == 512) {
    unsigned short* ws = (unsigned short*)d_ws;
    hipLaunchKernelGGL(prep_kernel, dim3(768), dim3(256), 0, stream,
                       Wq, bq, Wk, bk, Wv, bv, ws);
    hipLaunchKernelGGL(qkv_gemm_kernel, dim3(704, 4), dim3(256), 0, stream,
                       x, ws);
    hipLaunchKernelGGL(attn_kernel, dim3(4096), dim3(256), 0, stream,
                       (const unsigned short*)ws, (float*)d_out);
  } else {
    hipLaunchKernelGGL(mha_fused_kernel, dim3(B * NHEAD), dim3(BLK), 0, stream,
                       x, Wq, bq, Wk, bk, Wv, bv, (float*)d_out);
  }
}